// Round 1
// baseline (1366.449 us; speedup 1.0000x reference)
//
#include <hip/hip_runtime.h>
#include <math.h>

// Problem constants (fixed by the reference)
#define BB     2
#define LL     1024
#define CC     4
#define EE     256
#define HH     8
#define DD     32
#define NLAYER 2
#define W1N    257          // WIN+1
#define INPAIR 1028         // C*(WIN+1)
#define HIDN   512
#define NCN    10
#define SCALEF 0.17677669529663687f   // 32^-0.5

__device__ __forceinline__ float gelu_f(float x) {
    return 0.5f * x * (1.0f + erff(x * 0.7071067811865475f));
}

// ---------------------------------------------------------------------------
// Kernel 1: pair hidden = relu(flat @ pair_w1 + pair_b1)   [2048 x 256]
// flat is gathered on the fly from the diagonal window of x_pairwise.
// 128 threads, 8 rows/block, thread = 4 rows x 4 cols, w1 chunk staged in LDS.
// ---------------------------------------------------------------------------
__global__ __launch_bounds__(128) void pair_mlp1(
    const float* __restrict__ xp, const float* __restrict__ w1,
    const float* __restrict__ pb1, float* __restrict__ hp)
{
    __shared__ float As[8][64];
    __shared__ float Ws[32][256];
    const int t = threadIdx.x;
    const int row0 = blockIdx.x * 8;       // global row = b*L + l
    const int el = 4 * (t & 63);
    const int r0 = (t >> 6) * 4;
    float4 acc[4];
    #pragma unroll
    for (int r = 0; r < 4; ++r) { acc[r].x = 0.f; acc[r].y = 0.f; acc[r].z = 0.f; acc[r].w = 0.f; }

    for (int kb = 0; kb < INPAIR; kb += 32) {
        const int kt = (INPAIR - kb) < 32 ? (INPAIR - kb) : 32;
        // stage gathered A tile: 8 rows x kt
        for (int idx = t; idx < 8 * kt; idx += 128) {
            int r = idx / kt, kk = idx - r * kt;
            int kg = kb + kk;
            int c = kg / W1N, w = kg - c * W1N;
            int row = row0 + r;
            int b = row >> 10, l = row & 1023;
            int col = l + w - 128;
            float vv = 0.f;
            if (col >= 0 && col < LL) vv = xp[((b * CC + c) * LL + l) * LL + col];
            As[r][kk] = vv;
        }
        // stage W chunk: kt x 256
        for (int idx = t; idx < kt * 64; idx += 128) {
            int kk = idx >> 6, e4 = idx & 63;
            ((float4*)Ws[kk])[e4] = *(const float4*)(w1 + (kb + kk) * EE + 4 * e4);
        }
        __syncthreads();
        for (int kk = 0; kk < kt; kk += 4) {
            float4 a[4];
            #pragma unroll
            for (int r = 0; r < 4; ++r) a[r] = *((const float4*)As[r0 + r] + (kk >> 2));
            #pragma unroll
            for (int j = 0; j < 4; ++j) {
                float4 wv = *((const float4*)Ws[kk + j] + (t & 63));
                #pragma unroll
                for (int r = 0; r < 4; ++r) {
                    float av = ((const float*)&a[r])[j];
                    acc[r].x = fmaf(av, wv.x, acc[r].x);
                    acc[r].y = fmaf(av, wv.y, acc[r].y);
                    acc[r].z = fmaf(av, wv.z, acc[r].z);
                    acc[r].w = fmaf(av, wv.w, acc[r].w);
                }
            }
        }
        __syncthreads();
    }
    float4 bb = *(const float4*)(pb1 + el);
    #pragma unroll
    for (int r = 0; r < 4; ++r) {
        float4 o;
        o.x = fmaxf(acc[r].x + bb.x, 0.f);
        o.y = fmaxf(acc[r].y + bb.y, 0.f);
        o.z = fmaxf(acc[r].z + bb.z, 0.f);
        o.w = fmaxf(acc[r].w + bb.w, 0.f);
        *(float4*)(hp + (row0 + r0 + r) * EE + el) = o;
    }
}

// ---------------------------------------------------------------------------
// Generic 8-row GEMM:  out = epi(A(opt LN) @ W + bias)
// template: LNIN (layernorm staged A), ACT (0 none,1 relu,2 gelu),
//           RES (add res), QKVO (scatter to [B,H,L,D]), EMB (add emb+pe)
// grid.z selects (w,bias,out) triple (for fused QKV).
// ---------------------------------------------------------------------------
template<bool LNIN, int ACT, bool RES, bool QKVO, bool EMB>
__global__ __launch_bounds__(128) void gemm8(
    const float* __restrict__ A, int K, int N,
    const float* w0, const float* bi0, float* o0,
    const float* w1, const float* bi1, float* o1,
    const float* w2, const float* bi2, float* o2,
    const float* __restrict__ lng, const float* __restrict__ lnb,
    const float* __restrict__ res,
    const int* __restrict__ tokens, const float* __restrict__ temb,
    const float* __restrict__ pe)
{
    __shared__ float As[8][512];
    __shared__ float Ws[32][256];
    const int t = threadIdx.x;
    const int row0 = blockIdx.x * 8;
    const int cb = blockIdx.y * 256;
    const float* W; const float* bias; float* out;
    if (blockIdx.z == 0)      { W = w0; bias = bi0; out = o0; }
    else if (blockIdx.z == 1) { W = w1; bias = bi1; out = o1; }
    else                      { W = w2; bias = bi2; out = o2; }

    // stage A rows
    const int ksh = (K == 512) ? 7 : 6;
    const int kq = K >> 2;
    for (int idx = t; idx < 2 * K; idx += 128) {
        int r = idx >> ksh, c = idx & (kq - 1);
        *((float4*)As[r] + c) = *(const float4*)(A + (row0 + r) * K + 4 * c);
    }

    if constexpr (LNIN) {
        __syncthreads();
        const int lrow = t >> 4, ll = t & 15;
        float4* ar = (float4*)As[lrow];
        float4 v0 = ar[ll * 4 + 0], v1 = ar[ll * 4 + 1], v2 = ar[ll * 4 + 2], v3 = ar[ll * 4 + 3];
        float s = v0.x + v0.y + v0.z + v0.w + v1.x + v1.y + v1.z + v1.w
                + v2.x + v2.y + v2.z + v2.w + v3.x + v3.y + v3.z + v3.w;
        #pragma unroll
        for (int mm = 1; mm < 16; mm <<= 1) s += __shfl_xor(s, mm, 64);
        const float mu = s * (1.0f / 256.0f);
        float q2 = 0.f;
        {
            float d;
            d = v0.x - mu; q2 += d * d; d = v0.y - mu; q2 += d * d; d = v0.z - mu; q2 += d * d; d = v0.w - mu; q2 += d * d;
            d = v1.x - mu; q2 += d * d; d = v1.y - mu; q2 += d * d; d = v1.z - mu; q2 += d * d; d = v1.w - mu; q2 += d * d;
            d = v2.x - mu; q2 += d * d; d = v2.y - mu; q2 += d * d; d = v2.z - mu; q2 += d * d; d = v2.w - mu; q2 += d * d;
            d = v3.x - mu; q2 += d * d; d = v3.y - mu; q2 += d * d; d = v3.z - mu; q2 += d * d; d = v3.w - mu; q2 += d * d;
        }
        #pragma unroll
        for (int mm = 1; mm < 16; mm <<= 1) q2 += __shfl_xor(q2, mm, 64);
        const float rstd = rsqrtf(q2 * (1.0f / 256.0f) + 1e-5f);
        const int base = ll * 16;
        float4 g0 = *(const float4*)(lng + base + 0),  g1v = *(const float4*)(lng + base + 4);
        float4 g2v = *(const float4*)(lng + base + 8), g3v = *(const float4*)(lng + base + 12);
        float4 b0 = *(const float4*)(lnb + base + 0),  b1v = *(const float4*)(lnb + base + 4);
        float4 b2v = *(const float4*)(lnb + base + 8), b3v = *(const float4*)(lnb + base + 12);
        v0.x = (v0.x - mu) * rstd * g0.x + b0.x;  v0.y = (v0.y - mu) * rstd * g0.y + b0.y;
        v0.z = (v0.z - mu) * rstd * g0.z + b0.z;  v0.w = (v0.w - mu) * rstd * g0.w + b0.w;
        v1.x = (v1.x - mu) * rstd * g1v.x + b1v.x; v1.y = (v1.y - mu) * rstd * g1v.y + b1v.y;
        v1.z = (v1.z - mu) * rstd * g1v.z + b1v.z; v1.w = (v1.w - mu) * rstd * g1v.w + b1v.w;
        v2.x = (v2.x - mu) * rstd * g2v.x + b2v.x; v2.y = (v2.y - mu) * rstd * g2v.y + b2v.y;
        v2.z = (v2.z - mu) * rstd * g2v.z + b2v.z; v2.w = (v2.w - mu) * rstd * g2v.w + b2v.w;
        v3.x = (v3.x - mu) * rstd * g3v.x + b3v.x; v3.y = (v3.y - mu) * rstd * g3v.y + b3v.y;
        v3.z = (v3.z - mu) * rstd * g3v.z + b3v.z; v3.w = (v3.w - mu) * rstd * g3v.w + b3v.w;
        ar[ll * 4 + 0] = v0; ar[ll * 4 + 1] = v1; ar[ll * 4 + 2] = v2; ar[ll * 4 + 3] = v3;
        __syncthreads();
    }

    const int el = 4 * (t & 63);
    const int r0 = (t >> 6) * 4;
    float4 acc[4];
    #pragma unroll
    for (int r = 0; r < 4; ++r) { acc[r].x = 0.f; acc[r].y = 0.f; acc[r].z = 0.f; acc[r].w = 0.f; }

    for (int kb = 0; kb < K; kb += 32) {
        for (int idx = t; idx < 2048; idx += 128) {
            int kk = idx >> 6, e4 = idx & 63;
            ((float4*)Ws[kk])[e4] = *(const float4*)(W + (kb + kk) * N + cb + 4 * e4);
        }
        __syncthreads();
        #pragma unroll 2
        for (int kk = 0; kk < 32; kk += 4) {
            float4 a[4];
            #pragma unroll
            for (int r = 0; r < 4; ++r) a[r] = *((const float4*)As[r0 + r] + ((kb + kk) >> 2));
            #pragma unroll
            for (int j = 0; j < 4; ++j) {
                float4 wv = *((const float4*)Ws[kk + j] + (t & 63));
                #pragma unroll
                for (int r = 0; r < 4; ++r) {
                    float av = ((const float*)&a[r])[j];
                    acc[r].x = fmaf(av, wv.x, acc[r].x);
                    acc[r].y = fmaf(av, wv.y, acc[r].y);
                    acc[r].z = fmaf(av, wv.z, acc[r].z);
                    acc[r].w = fmaf(av, wv.w, acc[r].w);
                }
            }
        }
        __syncthreads();
    }

    float4 bb = *(const float4*)(bias + cb + el);
    #pragma unroll
    for (int r = 0; r < 4; ++r) {
        int row = row0 + r0 + r;
        float4 vv = acc[r];
        vv.x += bb.x; vv.y += bb.y; vv.z += bb.z; vv.w += bb.w;
        if constexpr (EMB) {
            int tok = tokens[row];
            float4 ev = *(const float4*)(temb + tok * EE + el);
            float4 pv = *(const float4*)(pe + (row & 1023) * EE + el);
            vv.x += ev.x + pv.x; vv.y += ev.y + pv.y; vv.z += ev.z + pv.z; vv.w += ev.w + pv.w;
        }
        if constexpr (ACT == 1) {
            vv.x = fmaxf(vv.x, 0.f); vv.y = fmaxf(vv.y, 0.f); vv.z = fmaxf(vv.z, 0.f); vv.w = fmaxf(vv.w, 0.f);
        } else if constexpr (ACT == 2) {
            vv.x = gelu_f(vv.x); vv.y = gelu_f(vv.y); vv.z = gelu_f(vv.z); vv.w = gelu_f(vv.w);
        }
        if constexpr (RES) {
            float4 rv = *(const float4*)(res + row * N + cb + el);
            vv.x += rv.x; vv.y += rv.y; vv.z += rv.z; vv.w += rv.w;
        }
        if constexpr (QKVO) {
            int b = row >> 10, l = row & 1023;
            int h = el >> 5, d = el & 31;
            *(float4*)(out + ((b * HH + h) * LL + l) * DD + d) = vv;
        } else {
            *(float4*)(out + row * N + cb + el) = vv;
        }
    }
}

// ---------------------------------------------------------------------------
// Fused attention (online softmax), fp32.  Block = (b, h, 64 q-rows).
// thread: 2 q-rows (rs = t>>3), m-subset { q8 + 8j } (q8 = t&7).
// ---------------------------------------------------------------------------
__global__ __launch_bounds__(256) void attn_fp32(
    const float* __restrict__ qb, const float* __restrict__ kbuf,
    const float* __restrict__ vbuf, const float* __restrict__ bias,
    const float* __restrict__ mask, const float* __restrict__ gate,
    float* __restrict__ ao)
{
    __shared__ float Ks[64][36];
    __shared__ float Vs[64][36];
    const int t = threadIdx.x;
    const int qt = blockIdx.x, h = blockIdx.y, b = blockIdx.z;
    const int q0 = qt * 64;
    const int bh = b * HH + h;
    const int rs = t >> 3;
    const int q8 = t & 7;
    const int r0 = rs * 2;
    const float gh = gate[h];

    float4 qr[2][8];
    #pragma unroll
    for (int rr = 0; rr < 2; ++rr) {
        const float* qp = qb + (bh * LL + q0 + r0 + rr) * DD;
        #pragma unroll
        for (int dc = 0; dc < 8; ++dc) qr[rr][dc] = *(const float4*)(qp + dc * 4);
    }
    float mrun0 = -3.0e38f, mrun1 = -3.0e38f, lrun0 = 0.f, lrun1 = 0.f;
    float4 O0[8], O1[8];
    #pragma unroll
    for (int dc = 0; dc < 8; ++dc) {
        O0[dc].x = O0[dc].y = O0[dc].z = O0[dc].w = 0.f;
        O1[dc].x = O1[dc].y = O1[dc].z = O1[dc].w = 0.f;
    }

    for (int mt = 0; mt < 16; ++mt) {
        const int m0 = mt * 64;
        for (int idx = t; idx < 512; idx += 256) {
            int row = idx >> 3, dc = idx & 7;
            *(float4*)&Ks[row][dc * 4] = *(const float4*)(kbuf + (bh * LL + m0 + row) * DD + dc * 4);
            *(float4*)&Vs[row][dc * 4] = *(const float4*)(vbuf + (bh * LL + m0 + row) * DD + dc * 4);
        }
        __syncthreads();

        float p0[8], p1[8];
        float tm0 = -3.0e38f, tm1 = -3.0e38f;
        #pragma unroll
        for (int j = 0; j < 8; ++j) {
            const int ml = q8 + 8 * j;
            const int mg = m0 + ml;
            float s0 = 0.f, s1 = 0.f;
            #pragma unroll
            for (int dc = 0; dc < 8; ++dc) {
                float4 kv = *(const float4*)&Ks[ml][dc * 4];
                s0 = fmaf(qr[0][dc].x, kv.x, s0); s0 = fmaf(qr[0][dc].y, kv.y, s0);
                s0 = fmaf(qr[0][dc].z, kv.z, s0); s0 = fmaf(qr[0][dc].w, kv.w, s0);
                s1 = fmaf(qr[1][dc].x, kv.x, s1); s1 = fmaf(qr[1][dc].y, kv.y, s1);
                s1 = fmaf(qr[1][dc].z, kv.z, s1); s1 = fmaf(qr[1][dc].w, kv.w, s1);
            }
            const float kbias = (1.0f - mask[b * LL + mg]) * (-10000.0f);
            const float bz0 = bias[(bh * LL + q0 + r0) * LL + mg];
            const float bz1 = bias[(bh * LL + q0 + r0 + 1) * LL + mg];
            s0 = fmaf(s0, SCALEF, fmaf(gh, bz0, kbias));
            s1 = fmaf(s1, SCALEF, fmaf(gh, bz1, kbias));
            p0[j] = s0; p1[j] = s1;
            tm0 = fmaxf(tm0, s0); tm1 = fmaxf(tm1, s1);
        }
        #pragma unroll
        for (int mm = 1; mm < 8; mm <<= 1) {
            tm0 = fmaxf(tm0, __shfl_xor(tm0, mm, 64));
            tm1 = fmaxf(tm1, __shfl_xor(tm1, mm, 64));
        }
        const float nm0 = fmaxf(mrun0, tm0), nm1 = fmaxf(mrun1, tm1);
        const float al0 = expf(mrun0 - nm0), al1 = expf(mrun1 - nm1);
        float ts0 = 0.f, ts1 = 0.f;
        #pragma unroll
        for (int j = 0; j < 8; ++j) {
            p0[j] = expf(p0[j] - nm0); ts0 += p0[j];
            p1[j] = expf(p1[j] - nm1); ts1 += p1[j];
        }
        #pragma unroll
        for (int mm = 1; mm < 8; mm <<= 1) {
            ts0 += __shfl_xor(ts0, mm, 64);
            ts1 += __shfl_xor(ts1, mm, 64);
        }
        lrun0 = lrun0 * al0 + ts0; lrun1 = lrun1 * al1 + ts1;
        mrun0 = nm0; mrun1 = nm1;
        #pragma unroll
        for (int dc = 0; dc < 8; ++dc) {
            O0[dc].x *= al0; O0[dc].y *= al0; O0[dc].z *= al0; O0[dc].w *= al0;
            O1[dc].x *= al1; O1[dc].y *= al1; O1[dc].z *= al1; O1[dc].w *= al1;
        }
        #pragma unroll
        for (int j = 0; j < 8; ++j) {
            const int ml = q8 + 8 * j;
            const float pj0 = p0[j], pj1 = p1[j];
            #pragma unroll
            for (int dc = 0; dc < 8; ++dc) {
                float4 vv = *(const float4*)&Vs[ml][dc * 4];
                O0[dc].x = fmaf(pj0, vv.x, O0[dc].x); O0[dc].y = fmaf(pj0, vv.y, O0[dc].y);
                O0[dc].z = fmaf(pj0, vv.z, O0[dc].z); O0[dc].w = fmaf(pj0, vv.w, O0[dc].w);
                O1[dc].x = fmaf(pj1, vv.x, O1[dc].x); O1[dc].y = fmaf(pj1, vv.y, O1[dc].y);
                O1[dc].z = fmaf(pj1, vv.z, O1[dc].z); O1[dc].w = fmaf(pj1, vv.w, O1[dc].w);
            }
        }
        __syncthreads();
    }
    // reduce partial O across the 8 m-subset threads
    #pragma unroll
    for (int mm = 1; mm < 8; mm <<= 1) {
        #pragma unroll
        for (int dc = 0; dc < 8; ++dc) {
            O0[dc].x += __shfl_xor(O0[dc].x, mm, 64); O0[dc].y += __shfl_xor(O0[dc].y, mm, 64);
            O0[dc].z += __shfl_xor(O0[dc].z, mm, 64); O0[dc].w += __shfl_xor(O0[dc].w, mm, 64);
            O1[dc].x += __shfl_xor(O1[dc].x, mm, 64); O1[dc].y += __shfl_xor(O1[dc].y, mm, 64);
            O1[dc].z += __shfl_xor(O1[dc].z, mm, 64); O1[dc].w += __shfl_xor(O1[dc].w, mm, 64);
        }
    }
    const float mq0 = mask[b * LL + q0 + r0];
    const float mq1 = mask[b * LL + q0 + r0 + 1];
    const float sc0 = (lrun0 > 0.f ? 1.0f / lrun0 : 0.f) * mq0 * mq0;
    const float sc1 = (lrun1 > 0.f ? 1.0f / lrun1 : 0.f) * mq1 * mq1;
    float4 o0 = O0[q8]; o0.x *= sc0; o0.y *= sc0; o0.z *= sc0; o0.w *= sc0;
    float4 o1 = O1[q8]; o1.x *= sc1; o1.y *= sc1; o1.z *= sc1; o1.w *= sc1;
    *(float4*)(ao + (b * LL + q0 + r0) * EE + h * DD + q8 * 4) = o0;
    *(float4*)(ao + (b * LL + q0 + r0 + 1) * EE + h * DD + q8 * 4) = o1;
}

// ---------------------------------------------------------------------------
// masked mean pool:  pooled[b][e]
// ---------------------------------------------------------------------------
__global__ __launch_bounds__(256) void pool_kernel(
    const float* __restrict__ x, const float* __restrict__ mask,
    float* __restrict__ pooled)
{
    const int b = blockIdx.x, e = threadIdx.x;
    float s = 0.f, ms = 0.f;
    for (int l = 0; l < LL; ++l) {
        float mm = mask[b * LL + l];
        s = fmaf(x[(b * LL + l) * EE + e], mm, s);
        ms += mm;
    }
    pooled[b * EE + e] = s / fmaxf(ms, 1.0f);
}

// ---------------------------------------------------------------------------
// head: LN + gelu(W1) + W2, single block
// ---------------------------------------------------------------------------
__global__ __launch_bounds__(256) void head_kernel(
    const float* __restrict__ pooled, const float* __restrict__ hg,
    const float* __restrict__ hb, const float* __restrict__ w1,
    const float* __restrict__ b1, const float* __restrict__ w2,
    const float* __restrict__ b2, float* __restrict__ outp)
{
    __shared__ float pn[EE];
    __shared__ float g1s[EE];
    __shared__ float red[4];
    const int t = threadIdx.x;
    for (int b = 0; b < BB; ++b) {
        float v = pooled[b * EE + t];
        float s = v;
        #pragma unroll
        for (int mm = 1; mm < 64; mm <<= 1) s += __shfl_xor(s, mm, 64);
        if ((t & 63) == 0) red[t >> 6] = s;
        __syncthreads();
        const float mu = (red[0] + red[1] + red[2] + red[3]) * (1.0f / 256.0f);
        __syncthreads();
        float d = v - mu;
        float q2 = d * d;
        #pragma unroll
        for (int mm = 1; mm < 64; mm <<= 1) q2 += __shfl_xor(q2, mm, 64);
        if ((t & 63) == 0) red[t >> 6] = q2;
        __syncthreads();
        const float var = (red[0] + red[1] + red[2] + red[3]) * (1.0f / 256.0f);
        const float rstd = rsqrtf(var + 1e-5f);
        pn[t] = d * rstd * hg[t] + hb[t];
        __syncthreads();
        float acc = b1[t];
        for (int k = 0; k < EE; ++k) acc = fmaf(pn[k], w1[k * EE + t], acc);
        g1s[t] = gelu_f(acc);
        __syncthreads();
        if (t < NCN) {
            float a2 = b2[t];
            for (int k = 0; k < EE; ++k) a2 = fmaf(g1s[k], w2[k * NCN + t], a2);
            outp[b * NCN + t] = a2;
        }
        __syncthreads();
    }
}

// ---------------------------------------------------------------------------
extern "C" void kernel_launch(void* const* d_in, const int* in_sizes, int n_in,
                              void* d_out, int out_size, void* d_ws, size_t ws_size,
                              hipStream_t stream) {
    const int*   tokens = (const int*)  d_in[0];
    const float* xp     = (const float*)d_in[1];
    const float* bias   = (const float*)d_in[2];
    const float* mask   = (const float*)d_in[3];
    const float* temb   = (const float*)d_in[4];
    const float* pe     = (const float*)d_in[5];
    const float* pw1    = (const float*)d_in[6];
    const float* pb1    = (const float*)d_in[7];
    const float* pw2    = (const float*)d_in[8];
    const float* pb2    = (const float*)d_in[9];
    const float* ln1g   = (const float*)d_in[10];
    const float* ln1b   = (const float*)d_in[11];
    const float* wq     = (const float*)d_in[12];
    const float* wk     = (const float*)d_in[13];
    const float* wv     = (const float*)d_in[14];
    const float* wo     = (const float*)d_in[15];
    const float* bq     = (const float*)d_in[16];
    const float* bk     = (const float*)d_in[17];
    const float* bv     = (const float*)d_in[18];
    const float* bo     = (const float*)d_in[19];
    const float* gate   = (const float*)d_in[20];
    const float* ln2g   = (const float*)d_in[21];
    const float* ln2b   = (const float*)d_in[22];
    const float* fw1    = (const float*)d_in[23];
    const float* fb1    = (const float*)d_in[24];
    const float* fw2    = (const float*)d_in[25];
    const float* fb2    = (const float*)d_in[26];
    const float* hlng   = (const float*)d_in[27];
    const float* hlnb   = (const float*)d_in[28];
    const float* hw1    = (const float*)d_in[29];
    const float* hb1    = (const float*)d_in[30];
    const float* hw2    = (const float*)d_in[31];
    const float* hb2    = (const float*)d_in[32];

    float* ws = (float*)d_ws;
    const size_t NTOK = (size_t)BB * LL * EE;   // 524288
    float* x      = ws;
    float* qbuf   = ws + NTOK;
    float* kbuf   = ws + 2 * NTOK;
    float* vbuf   = ws + 3 * NTOK;
    float* ao     = ws + 4 * NTOK;
    float* ffh    = ws + 5 * NTOK;              // 1048576 floats (also pair hidden)
    float* pooled = ws + 5 * NTOK + (size_t)BB * LL * HIDN;

    // 1) pair projector MLP1 (gather + relu GEMM) -> ffh
    pair_mlp1<<<dim3(256), dim3(128), 0, stream>>>(xp, pw1, pb1, ffh);
    // 2) pair MLP2 + token emb + pe -> x
    gemm8<false, 0, false, false, true><<<dim3(256, 1, 1), dim3(128), 0, stream>>>(
        ffh, 256, 256, pw2, pb2, x, pw2, pb2, x, pw2, pb2, x,
        nullptr, nullptr, nullptr, tokens, temb, pe);

    for (int i = 0; i < NLAYER; ++i) {
        // QKV (LN fused), one launch, z = 3
        gemm8<true, 0, false, true, false><<<dim3(256, 1, 3), dim3(128), 0, stream>>>(
            x, 256, 256,
            wq + i * EE * EE, bq + i * EE, qbuf,
            wk + i * EE * EE, bk + i * EE, kbuf,
            wv + i * EE * EE, bv + i * EE, vbuf,
            ln1g + i * EE, ln1b + i * EE, nullptr, nullptr, nullptr, nullptr);
        // fused attention
        attn_fp32<<<dim3(16, HH, BB), dim3(256), 0, stream>>>(
            qbuf, kbuf, vbuf, bias, mask, gate + i * HH, ao);
        // out projection + residual
        gemm8<false, 0, true, false, false><<<dim3(256, 1, 1), dim3(128), 0, stream>>>(
            ao, 256, 256, wo + i * EE * EE, bo + i * EE, x,
            wo + i * EE * EE, bo + i * EE, x, wo + i * EE * EE, bo + i * EE, x,
            nullptr, nullptr, x, nullptr, nullptr, nullptr);
        // FFN1: gelu(LN(x) @ fw1 + fb1) -> ffh   (N=512, 2 col blocks)
        gemm8<true, 2, false, false, false><<<dim3(256, 2, 1), dim3(128), 0, stream>>>(
            x, 256, 512, fw1 + i * EE * HIDN, fb1 + i * HIDN, ffh,
            fw1 + i * EE * HIDN, fb1 + i * HIDN, ffh,
            fw1 + i * EE * HIDN, fb1 + i * HIDN, ffh,
            ln2g + i * EE, ln2b + i * EE, nullptr, nullptr, nullptr, nullptr);
        // FFN2: x += ffh @ fw2 + fb2   (K=512)
        gemm8<false, 0, true, false, false><<<dim3(256, 1, 1), dim3(128), 0, stream>>>(
            ffh, 512, 256, fw2 + i * HIDN * EE, fb2 + i * EE, x,
            fw2 + i * HIDN * EE, fb2 + i * EE, x,
            fw2 + i * HIDN * EE, fb2 + i * EE, x,
            nullptr, nullptr, x, nullptr, nullptr, nullptr);
    }

    pool_kernel<<<dim3(BB), dim3(256), 0, stream>>>(x, mask, pooled);
    head_kernel<<<dim3(1), dim3(256), 0, stream>>>(
        pooled, hlng, hlnb, hw1, hb1, hw2, hb2, (float*)d_out);

    (void)in_sizes; (void)n_in; (void)out_size; (void)ws_size;
}

// Round 2
// 907.508 us; speedup vs baseline: 1.5057x; 1.5057x over previous
//
#include <hip/hip_runtime.h>
#include <math.h>

// Problem constants (fixed by the reference)
#define BB     2
#define LL     1024
#define CC     4
#define EE     256
#define HH     8
#define DD     32
#define NLAYER 2
#define W1N    257          // WIN+1
#define INPAIR 1028         // C*(WIN+1)
#define KCH    257          // per-channel K chunk of pair MLP1
#define HIDN   512
#define NCN    10
#define SCALEF 0.17677669529663687f   // 32^-0.5

__device__ __forceinline__ float gelu_f(float x) {
    return 0.5f * x * (1.0f + erff(x * 0.7071067811865475f));
}

// ---------------------------------------------------------------------------
// pair_partial: hpart[c] = flat_c @ w1_c   (per-channel split-K partial, no
// bias/relu — fused into the MLP2 A-stage). Grid (M/8, 4). 128 thr, 16 out/thr.
// ---------------------------------------------------------------------------
__global__ __launch_bounds__(128) void pair_partial(
    const float* __restrict__ xp, const float* __restrict__ w1,
    float* __restrict__ hpart)
{
    __shared__ float As[8][32];
    __shared__ float Ws[32][256];
    const int t = threadIdx.x;
    const int row0 = blockIdx.x * 8;       // global row = b*L + l
    const int c = blockIdx.y;              // pairwise channel = K chunk
    const int el = 4 * (t & 63);
    const int r0 = (t >> 6) * 4;
    float4 acc[4];
    #pragma unroll
    for (int r = 0; r < 4; ++r) { acc[r].x = 0.f; acc[r].y = 0.f; acc[r].z = 0.f; acc[r].w = 0.f; }

    for (int kb = 0; kb < 288; kb += 32) {          // 9 chunks cover K=257 (pad 0)
        // stage gathered A tile: 8 rows x 32
        for (int idx = t; idx < 256; idx += 128) {
            int r = idx >> 5, kk = idx & 31;
            int k = kb + kk;
            int row = row0 + r;
            int b = row >> 10, l = row & 1023;
            int col = l + k - 128;
            float vv = 0.f;
            if (k < KCH && col >= 0 && col < LL)
                vv = xp[(((size_t)(b * CC + c) * LL + l) * LL) + col];
            As[r][kk] = vv;
        }
        // stage W chunk: 32 x 256 (zero-pad beyond 257)
        for (int idx = t; idx < 2048; idx += 128) {
            int kk = idx >> 6, e4 = idx & 63;
            int k = kb + kk;
            float4 wv;
            if (k < KCH) wv = *(const float4*)(w1 + (size_t)(c * KCH + k) * EE + 4 * e4);
            else { wv.x = wv.y = wv.z = wv.w = 0.f; }
            ((float4*)Ws[kk])[e4] = wv;
        }
        __syncthreads();
        #pragma unroll 2
        for (int kk = 0; kk < 32; kk += 4) {
            float4 a[4];
            #pragma unroll
            for (int r = 0; r < 4; ++r) a[r] = *((const float4*)As[r0 + r] + (kk >> 2));
            #pragma unroll
            for (int j = 0; j < 4; ++j) {
                float4 wv = *((const float4*)Ws[kk + j] + (t & 63));
                #pragma unroll
                for (int r = 0; r < 4; ++r) {
                    float av = ((const float*)&a[r])[j];
                    acc[r].x = fmaf(av, wv.x, acc[r].x);
                    acc[r].y = fmaf(av, wv.y, acc[r].y);
                    acc[r].z = fmaf(av, wv.z, acc[r].z);
                    acc[r].w = fmaf(av, wv.w, acc[r].w);
                }
            }
        }
        __syncthreads();
    }
    #pragma unroll
    for (int r = 0; r < 4; ++r)
        *(float4*)(hpart + ((size_t)c * 2048 + row0 + r0 + r) * EE + el) = acc[r];
}

// ---------------------------------------------------------------------------
// Generic GEMM:  out = epi(A(opt LN / pair-sum) @ W + bias)
// Tile 8 rows x 128 cols, 128 threads, 8 out/thr. Grid (M/8, N/128, z).
// ---------------------------------------------------------------------------
template<int K, int N, bool LNIN, int ACT, bool RES, bool QKVO, bool EMB, bool PAIRIN>
__global__ __launch_bounds__(128) void gemm8(
    const float* __restrict__ A,
    const float* W0, const float* B0, float* O0p,
    const float* W1p, const float* B1p, float* O1p,
    const float* W2p, const float* B2p, float* O2p,
    const float* __restrict__ lng, const float* __restrict__ lnb,
    const float* __restrict__ res,
    const int* __restrict__ tokens, const float* __restrict__ temb,
    const float* __restrict__ pe, const float* __restrict__ pairb)
{
    __shared__ float As[8][K];
    __shared__ float Ws[32][128];
    const int t = threadIdx.x;
    const int row0 = blockIdx.x * 8;
    const int cb = blockIdx.y * 128;
    const float* W; const float* bias; float* out;
    if (blockIdx.z == 0)      { W = W0;  bias = B0;  out = O0p; }
    else if (blockIdx.z == 1) { W = W1p; bias = B1p; out = O1p; }
    else                      { W = W2p; bias = B2p; out = O2p; }

    // stage A rows
    if constexpr (PAIRIN) {
        // A = hpart base [4][2048][256]; sum channels + pair_b1, relu
        for (int idx = t; idx < 8 * 64; idx += 128) {
            int r = idx >> 6, e4 = idx & 63;
            int row = row0 + r;
            float4 s = *(const float4*)(pairb + 4 * e4);
            #pragma unroll
            for (int c = 0; c < 4; ++c) {
                float4 hv = *(const float4*)(A + ((size_t)c * 2048 + row) * EE + 4 * e4);
                s.x += hv.x; s.y += hv.y; s.z += hv.z; s.w += hv.w;
            }
            s.x = fmaxf(s.x, 0.f); s.y = fmaxf(s.y, 0.f);
            s.z = fmaxf(s.z, 0.f); s.w = fmaxf(s.w, 0.f);
            ((float4*)As[r])[e4] = s;
        }
    } else {
        constexpr int KQ = K >> 2;
        for (int idx = t; idx < 2 * K; idx += 128) {
            int r = idx / KQ, cc = idx & (KQ - 1);
            ((float4*)As[r])[cc] = *(const float4*)(A + (size_t)(row0 + r) * K + 4 * cc);
        }
    }

    if constexpr (LNIN) {
        __syncthreads();
        const int lrow = t >> 4, ll = t & 15;
        float4* ar = (float4*)As[lrow];
        float4 v0 = ar[ll * 4 + 0], v1 = ar[ll * 4 + 1], v2 = ar[ll * 4 + 2], v3 = ar[ll * 4 + 3];
        float s = v0.x + v0.y + v0.z + v0.w + v1.x + v1.y + v1.z + v1.w
                + v2.x + v2.y + v2.z + v2.w + v3.x + v3.y + v3.z + v3.w;
        #pragma unroll
        for (int mm = 1; mm < 16; mm <<= 1) s += __shfl_xor(s, mm, 64);
        const float mu = s * (1.0f / 256.0f);
        float q2 = 0.f;
        {
            float d;
            d = v0.x - mu; q2 += d * d; d = v0.y - mu; q2 += d * d; d = v0.z - mu; q2 += d * d; d = v0.w - mu; q2 += d * d;
            d = v1.x - mu; q2 += d * d; d = v1.y - mu; q2 += d * d; d = v1.z - mu; q2 += d * d; d = v1.w - mu; q2 += d * d;
            d = v2.x - mu; q2 += d * d; d = v2.y - mu; q2 += d * d; d = v2.z - mu; q2 += d * d; d = v2.w - mu; q2 += d * d;
            d = v3.x - mu; q2 += d * d; d = v3.y - mu; q2 += d * d; d = v3.z - mu; q2 += d * d; d = v3.w - mu; q2 += d * d;
        }
        #pragma unroll
        for (int mm = 1; mm < 16; mm <<= 1) q2 += __shfl_xor(q2, mm, 64);
        const float rstd = rsqrtf(q2 * (1.0f / 256.0f) + 1e-5f);
        const int base = ll * 16;
        float4 g0 = *(const float4*)(lng + base + 0),  g1v = *(const float4*)(lng + base + 4);
        float4 g2v = *(const float4*)(lng + base + 8), g3v = *(const float4*)(lng + base + 12);
        float4 b0 = *(const float4*)(lnb + base + 0),  b1v = *(const float4*)(lnb + base + 4);
        float4 b2v = *(const float4*)(lnb + base + 8), b3v = *(const float4*)(lnb + base + 12);
        v0.x = (v0.x - mu) * rstd * g0.x + b0.x;  v0.y = (v0.y - mu) * rstd * g0.y + b0.y;
        v0.z = (v0.z - mu) * rstd * g0.z + b0.z;  v0.w = (v0.w - mu) * rstd * g0.w + b0.w;
        v1.x = (v1.x - mu) * rstd * g1v.x + b1v.x; v1.y = (v1.y - mu) * rstd * g1v.y + b1v.y;
        v1.z = (v1.z - mu) * rstd * g1v.z + b1v.z; v1.w = (v1.w - mu) * rstd * g1v.w + b1v.w;
        v2.x = (v2.x - mu) * rstd * g2v.x + b2v.x; v2.y = (v2.y - mu) * rstd * g2v.y + b2v.y;
        v2.z = (v2.z - mu) * rstd * g2v.z + b2v.z; v2.w = (v2.w - mu) * rstd * g2v.w + b2v.w;
        v3.x = (v3.x - mu) * rstd * g3v.x + b3v.x; v3.y = (v3.y - mu) * rstd * g3v.y + b3v.y;
        v3.z = (v3.z - mu) * rstd * g3v.z + b3v.z; v3.w = (v3.w - mu) * rstd * g3v.w + b3v.w;
        ar[ll * 4 + 0] = v0; ar[ll * 4 + 1] = v1; ar[ll * 4 + 2] = v2; ar[ll * 4 + 3] = v3;
    }

    const int c4 = t & 31;        // col float4 index (128 cols)
    const int rp = t >> 5;        // row pair 0..3
    float4 acc0, acc1;
    acc0.x = acc0.y = acc0.z = acc0.w = 0.f;
    acc1.x = acc1.y = acc1.z = acc1.w = 0.f;

    for (int kb = 0; kb < K; kb += 32) {
        __syncthreads();  // As visible (first iter) / prev compute done
        for (int idx = t; idx < 1024; idx += 128) {
            int kk = idx >> 5, e4 = idx & 31;
            ((float4*)Ws[kk])[e4] = *(const float4*)(W + (size_t)(kb + kk) * N + cb + 4 * e4);
        }
        __syncthreads();
        #pragma unroll 4
        for (int kk = 0; kk < 32; kk += 4) {
            float4 a0 = ((const float4*)As[rp * 2 + 0])[(kb + kk) >> 2];
            float4 a1 = ((const float4*)As[rp * 2 + 1])[(kb + kk) >> 2];
            #pragma unroll
            for (int j = 0; j < 4; ++j) {
                float4 wv = ((const float4*)Ws[kk + j])[c4];
                float av0 = ((const float*)&a0)[j];
                float av1 = ((const float*)&a1)[j];
                acc0.x = fmaf(av0, wv.x, acc0.x); acc0.y = fmaf(av0, wv.y, acc0.y);
                acc0.z = fmaf(av0, wv.z, acc0.z); acc0.w = fmaf(av0, wv.w, acc0.w);
                acc1.x = fmaf(av1, wv.x, acc1.x); acc1.y = fmaf(av1, wv.y, acc1.y);
                acc1.z = fmaf(av1, wv.z, acc1.z); acc1.w = fmaf(av1, wv.w, acc1.w);
            }
        }
    }

    const int col = cb + 4 * c4;
    float4 bb = *(const float4*)(bias + col);
    float4 accs[2] = {acc0, acc1};
    #pragma unroll
    for (int rr = 0; rr < 2; ++rr) {
        int row = row0 + rp * 2 + rr;
        float4 vv = accs[rr];
        vv.x += bb.x; vv.y += bb.y; vv.z += bb.z; vv.w += bb.w;
        if constexpr (EMB) {
            int tok = tokens[row];
            float4 ev = *(const float4*)(temb + (size_t)tok * EE + col);
            float4 pv = *(const float4*)(pe + (size_t)(row & 1023) * EE + col);
            vv.x += ev.x + pv.x; vv.y += ev.y + pv.y; vv.z += ev.z + pv.z; vv.w += ev.w + pv.w;
        }
        if constexpr (ACT == 1) {
            vv.x = fmaxf(vv.x, 0.f); vv.y = fmaxf(vv.y, 0.f); vv.z = fmaxf(vv.z, 0.f); vv.w = fmaxf(vv.w, 0.f);
        } else if constexpr (ACT == 2) {
            vv.x = gelu_f(vv.x); vv.y = gelu_f(vv.y); vv.z = gelu_f(vv.z); vv.w = gelu_f(vv.w);
        }
        if constexpr (RES) {
            float4 rv = *(const float4*)(res + (size_t)row * N + col);
            vv.x += rv.x; vv.y += rv.y; vv.z += rv.z; vv.w += rv.w;
        }
        if constexpr (QKVO) {
            int b = row >> 10, l = row & 1023;
            int h = col >> 5, d = col & 31;
            *(float4*)(out + (((size_t)(b * HH + h) * LL + l) * DD) + d) = vv;
        } else {
            *(float4*)(out + (size_t)row * N + col) = vv;
        }
    }
}

// ---------------------------------------------------------------------------
// Fused attention (online softmax), fp32.  Block = (32 q-rows, h, b).
// 256 threads: 1 q-row/thread (rs = t>>3), m-subset q8 = t&7.
// ---------------------------------------------------------------------------
__global__ __launch_bounds__(256) void attn_fp32(
    const float* __restrict__ qb, const float* __restrict__ kbuf,
    const float* __restrict__ vbuf, const float* __restrict__ bias,
    const float* __restrict__ mask, const float* __restrict__ gate,
    float* __restrict__ ao)
{
    __shared__ float Ks[64][36];
    __shared__ float Vs[64][36];
    const int t = threadIdx.x;
    const int h = blockIdx.y, b = blockIdx.z;
    const int q0 = blockIdx.x * 32;
    const int bh = b * HH + h;
    const int rs = t >> 3;
    const int q8 = t & 7;
    const int row = q0 + rs;
    const float gh = gate[h];

    float4 qr[8];
    {
        const float* qp = qb + ((size_t)bh * LL + row) * DD;
        #pragma unroll
        for (int dc = 0; dc < 8; ++dc) qr[dc] = *(const float4*)(qp + dc * 4);
    }
    float mrun = -3.0e38f, lrun = 0.f;
    float4 O[8];
    #pragma unroll
    for (int dc = 0; dc < 8; ++dc) { O[dc].x = O[dc].y = O[dc].z = O[dc].w = 0.f; }

    const float* brow = bias + ((size_t)bh * LL + row) * LL;

    for (int mt = 0; mt < 16; ++mt) {
        const int m0 = mt * 64;
        for (int idx = t; idx < 512; idx += 256) {
            int r = idx >> 3, dc = idx & 7;
            *(float4*)&Ks[r][dc * 4] = *(const float4*)(kbuf + ((size_t)bh * LL + m0 + r) * DD + dc * 4);
            *(float4*)&Vs[r][dc * 4] = *(const float4*)(vbuf + ((size_t)bh * LL + m0 + r) * DD + dc * 4);
        }
        __syncthreads();

        float p[8];
        float tm = -3.0e38f;
        #pragma unroll
        for (int j = 0; j < 8; ++j) {
            const int ml = q8 + 8 * j;
            const int mg = m0 + ml;
            float s = 0.f;
            #pragma unroll
            for (int dc = 0; dc < 8; ++dc) {
                float4 kv = *(const float4*)&Ks[ml][dc * 4];
                s = fmaf(qr[dc].x, kv.x, s); s = fmaf(qr[dc].y, kv.y, s);
                s = fmaf(qr[dc].z, kv.z, s); s = fmaf(qr[dc].w, kv.w, s);
            }
            const float kbias = (1.0f - mask[b * LL + mg]) * (-10000.0f);
            s = fmaf(s, SCALEF, fmaf(gh, brow[mg], kbias));
            p[j] = s;
            tm = fmaxf(tm, s);
        }
        #pragma unroll
        for (int mm = 1; mm < 8; mm <<= 1) tm = fmaxf(tm, __shfl_xor(tm, mm, 64));
        const float nm = fmaxf(mrun, tm);
        const float al = expf(mrun - nm);
        float ts = 0.f;
        #pragma unroll
        for (int j = 0; j < 8; ++j) { p[j] = expf(p[j] - nm); ts += p[j]; }
        #pragma unroll
        for (int mm = 1; mm < 8; mm <<= 1) ts += __shfl_xor(ts, mm, 64);
        lrun = lrun * al + ts;
        mrun = nm;
        #pragma unroll
        for (int dc = 0; dc < 8; ++dc) {
            O[dc].x *= al; O[dc].y *= al; O[dc].z *= al; O[dc].w *= al;
        }
        #pragma unroll
        for (int j = 0; j < 8; ++j) {
            const int ml = q8 + 8 * j;
            const float pj = p[j];
            #pragma unroll
            for (int dc = 0; dc < 8; ++dc) {
                float4 vv = *(const float4*)&Vs[ml][dc * 4];
                O[dc].x = fmaf(pj, vv.x, O[dc].x); O[dc].y = fmaf(pj, vv.y, O[dc].y);
                O[dc].z = fmaf(pj, vv.z, O[dc].z); O[dc].w = fmaf(pj, vv.w, O[dc].w);
            }
        }
        __syncthreads();
    }
    // reduce partial O across the 8 m-subset threads
    #pragma unroll
    for (int mm = 1; mm < 8; mm <<= 1) {
        #pragma unroll
        for (int dc = 0; dc < 8; ++dc) {
            O[dc].x += __shfl_xor(O[dc].x, mm, 64); O[dc].y += __shfl_xor(O[dc].y, mm, 64);
            O[dc].z += __shfl_xor(O[dc].z, mm, 64); O[dc].w += __shfl_xor(O[dc].w, mm, 64);
        }
    }
    const float mq = mask[b * LL + row];
    const float sc = (lrun > 0.f ? 1.0f / lrun : 0.f) * mq * mq;
    float4 o = O[q8];
    o.x *= sc; o.y *= sc; o.z *= sc; o.w *= sc;
    *(float4*)(ao + ((size_t)(b * LL + row)) * EE + h * DD + q8 * 4) = o;
}

// ---------------------------------------------------------------------------
// pool stage 1: partial sums over 128-row chunks
// ---------------------------------------------------------------------------
__global__ __launch_bounds__(256) void pool_part(
    const float* __restrict__ x, const float* __restrict__ mask,
    float* __restrict__ part, float* __restrict__ pmask)
{
    const int ch = blockIdx.x, b = blockIdx.y, t = threadIdx.x;
    const int l0 = ch * 128;
    float s = 0.f, ms = 0.f;
    for (int i = 0; i < 128; ++i) {
        int l = l0 + i;
        float mm = mask[b * LL + l];
        s = fmaf(x[((size_t)(b * LL + l)) * EE + t], mm, s);
        ms += mm;
    }
    part[(size_t)(b * 8 + ch) * EE + t] = s;
    if (t == 0) pmask[b * 8 + ch] = ms;
}

// ---------------------------------------------------------------------------
// head: pool-reduce + LN + gelu(W1) + W2, single block
// ---------------------------------------------------------------------------
__global__ __launch_bounds__(256) void head_kernel(
    const float* __restrict__ part, const float* __restrict__ pmask,
    const float* __restrict__ hg, const float* __restrict__ hb,
    const float* __restrict__ w1, const float* __restrict__ b1,
    const float* __restrict__ w2, const float* __restrict__ b2,
    float* __restrict__ outp)
{
    __shared__ float pn[EE];
    __shared__ float g1s[EE];
    __shared__ float red[4];
    const int t = threadIdx.x;
    for (int b = 0; b < BB; ++b) {
        float v = 0.f, msum = 0.f;
        #pragma unroll
        for (int c = 0; c < 8; ++c) {
            v += part[(size_t)(b * 8 + c) * EE + t];
            msum += pmask[b * 8 + c];
        }
        v = v / fmaxf(msum, 1.0f);
        float s = v;
        #pragma unroll
        for (int mm = 1; mm < 64; mm <<= 1) s += __shfl_xor(s, mm, 64);
        if ((t & 63) == 0) red[t >> 6] = s;
        __syncthreads();
        const float mu = (red[0] + red[1] + red[2] + red[3]) * (1.0f / 256.0f);
        __syncthreads();
        float d = v - mu;
        float q2 = d * d;
        #pragma unroll
        for (int mm = 1; mm < 64; mm <<= 1) q2 += __shfl_xor(q2, mm, 64);
        if ((t & 63) == 0) red[t >> 6] = q2;
        __syncthreads();
        const float var = (red[0] + red[1] + red[2] + red[3]) * (1.0f / 256.0f);
        const float rstd = rsqrtf(var + 1e-5f);
        pn[t] = d * rstd * hg[t] + hb[t];
        __syncthreads();
        float acc = b1[t];
        for (int k = 0; k < EE; ++k) acc = fmaf(pn[k], w1[k * EE + t], acc);
        g1s[t] = gelu_f(acc);
        __syncthreads();
        if (t < NCN) {
            float a2 = b2[t];
            for (int k = 0; k < EE; ++k) a2 = fmaf(g1s[k], w2[k * NCN + t], a2);
            outp[b * NCN + t] = a2;
        }
        __syncthreads();
    }
}

// ---------------------------------------------------------------------------
extern "C" void kernel_launch(void* const* d_in, const int* in_sizes, int n_in,
                              void* d_out, int out_size, void* d_ws, size_t ws_size,
                              hipStream_t stream) {
    const int*   tokens = (const int*)  d_in[0];
    const float* xp     = (const float*)d_in[1];
    const float* bias   = (const float*)d_in[2];
    const float* mask   = (const float*)d_in[3];
    const float* temb   = (const float*)d_in[4];
    const float* pe     = (const float*)d_in[5];
    const float* pw1    = (const float*)d_in[6];
    const float* pb1    = (const float*)d_in[7];
    const float* pw2    = (const float*)d_in[8];
    const float* pb2    = (const float*)d_in[9];
    const float* ln1g   = (const float*)d_in[10];
    const float* ln1b   = (const float*)d_in[11];
    const float* wq     = (const float*)d_in[12];
    const float* wk     = (const float*)d_in[13];
    const float* wv     = (const float*)d_in[14];
    const float* wo     = (const float*)d_in[15];
    const float* bq     = (const float*)d_in[16];
    const float* bk     = (const float*)d_in[17];
    const float* bv     = (const float*)d_in[18];
    const float* bo     = (const float*)d_in[19];
    const float* gate   = (const float*)d_in[20];
    const float* ln2g   = (const float*)d_in[21];
    const float* ln2b   = (const float*)d_in[22];
    const float* fw1    = (const float*)d_in[23];
    const float* fb1    = (const float*)d_in[24];
    const float* fw2    = (const float*)d_in[25];
    const float* fb2    = (const float*)d_in[26];
    const float* hlng   = (const float*)d_in[27];
    const float* hlnb   = (const float*)d_in[28];
    const float* hw1    = (const float*)d_in[29];
    const float* hb1    = (const float*)d_in[30];
    const float* hw2    = (const float*)d_in[31];
    const float* hb2    = (const float*)d_in[32];

    float* ws = (float*)d_ws;
    const size_t NTOK = (size_t)BB * LL * EE;   // 524288
    float* x      = ws;
    float* qbuf   = ws + NTOK;
    float* kbuf   = ws + 2 * NTOK;
    float* vbuf   = ws + 3 * NTOK;
    float* ao     = ws + 4 * NTOK;
    float* hpart  = qbuf;                        // [4][2048][256] overlaps q/k/v/ao (consumed before QKV)
    float* ffh    = ws + 5 * NTOK;               // [2048][512]
    float* part   = ws + 5 * NTOK + (size_t)BB * LL * HIDN;
    float* pmaskp = part + 16 * EE;

    // 1) pair projector MLP1 partials (split-K by channel)
    pair_partial<<<dim3(256, 4), dim3(128), 0, stream>>>(xp, pw1, hpart);
    // 2) pair MLP2 (sum partials + b1 + relu in A-stage) + token emb + pe -> x
    gemm8<256, 256, false, 0, false, false, true, true><<<dim3(256, 2, 1), dim3(128), 0, stream>>>(
        hpart, pw2, pb2, x, pw2, pb2, x, pw2, pb2, x,
        nullptr, nullptr, nullptr, tokens, temb, pe, pb1);

    for (int i = 0; i < NLAYER; ++i) {
        // QKV (LN fused), one launch, z = 3
        gemm8<256, 256, true, 0, false, true, false, false><<<dim3(256, 2, 3), dim3(128), 0, stream>>>(
            x,
            wq + i * EE * EE, bq + i * EE, qbuf,
            wk + i * EE * EE, bk + i * EE, kbuf,
            wv + i * EE * EE, bv + i * EE, vbuf,
            ln1g + i * EE, ln1b + i * EE, nullptr, nullptr, nullptr, nullptr, nullptr);
        // fused attention
        attn_fp32<<<dim3(32, HH, BB), dim3(256), 0, stream>>>(
            qbuf, kbuf, vbuf, bias, mask, gate + i * HH, ao);
        // out projection + residual
        gemm8<256, 256, false, 0, true, false, false, false><<<dim3(256, 2, 1), dim3(128), 0, stream>>>(
            ao, wo + i * EE * EE, bo + i * EE, x,
            wo + i * EE * EE, bo + i * EE, x, wo + i * EE * EE, bo + i * EE, x,
            nullptr, nullptr, x, nullptr, nullptr, nullptr, nullptr);
        // FFN1: gelu(LN(x) @ fw1 + fb1) -> ffh
        gemm8<256, 512, true, 2, false, false, false, false><<<dim3(256, 4, 1), dim3(128), 0, stream>>>(
            x, fw1 + i * EE * HIDN, fb1 + i * HIDN, ffh,
            fw1 + i * EE * HIDN, fb1 + i * HIDN, ffh,
            fw1 + i * EE * HIDN, fb1 + i * HIDN, ffh,
            ln2g + i * EE, ln2b + i * EE, nullptr, nullptr, nullptr, nullptr, nullptr);
        // FFN2: x += ffh @ fw2 + fb2
        gemm8<512, 256, false, 0, true, false, false, false><<<dim3(256, 2, 1), dim3(128), 0, stream>>>(
            ffh, fw2 + i * HIDN * EE, fb2 + i * EE, x,
            fw2 + i * HIDN * EE, fb2 + i * EE, x,
            fw2 + i * HIDN * EE, fb2 + i * EE, x,
            nullptr, nullptr, x, nullptr, nullptr, nullptr, nullptr);
    }

    pool_part<<<dim3(8, BB), dim3(256), 0, stream>>>(x, mask, part, pmaskp);
    head_kernel<<<dim3(1), dim3(256), 0, stream>>>(
        part, pmaskp, hlng, hlnb, hw1, hb1, hw2, hb2, (float*)d_out);

    (void)in_sizes; (void)n_in; (void)out_size; (void)ws_size;
}